// Round 1
// 742.902 us; speedup vs baseline: 1.1763x; 1.1763x over previous
//
#include <hip/hip_runtime.h>

// F2FConv3d on MI355X.
// contrib = (x ⊗ bary) @ Wflat  as f16 MFMA (16x16x32), W = A-operand in registers (AGPRs).
// K ordering: p = kbasis*64 + i  (chunk c of 32: kbasis = c>>1, i = (c&1)*32 + [0,32)).
// Wave w owns output channels [w*16, w*16+16): A-frags = 18 x half8 = 72 regs, loaded once.
// V2: depth-1 register software-pipeline (next tile's X/BARY loads issued before current
//     MFMA+reduce phase), dual accumulators (chain 18 -> 9), setprio around MFMA, rcpf.
// D layout (measured, m89): row = quad*4 + reg (channel), col = lane&15 (texture)
//   -> facet (4 consecutive textures) = shfl_xor 1,2 across lanes.

typedef _Float16 half8  __attribute__((ext_vector_type(8)));
typedef _Float16 h2     __attribute__((ext_vector_type(2)));
typedef __fp16   fp16x2 __attribute__((ext_vector_type(2)));
typedef float    f32x4  __attribute__((ext_vector_type(4)));
typedef float    f32x4u __attribute__((ext_vector_type(4), aligned(4)));

#define NGROUPS 100000   // 1.6M textures / 16 per group
#define FFACETS 400000
#define GRID1   1024

union HF { h2 h[4]; half8 v; };

static __device__ __forceinline__ h2 pkrtz(float a, float b) {
    fp16x2 r = __builtin_amdgcn_cvt_pkrtz(a, b);
    return __builtin_bit_cast(h2, r);
}

// ---- kernel 1: swizzle W (fp32 [64][64][9]) -> f16 fragment order in ws, zero stats
__global__ __launch_bounds__(256) void prep_kernel(const float* __restrict__ W,
                                                   _Float16* __restrict__ wswz,
                                                   float* __restrict__ stats) {
    int idx = blockIdx.x * 256 + threadIdx.x;
    if (idx < 36864) {
        int j    = idx & 7;
        int lane = (idx >> 3) & 63;
        int mt   = (idx >> 9) & 3;        // which wave (channel tile)
        int c    = idx >> 11;             // K chunk 0..17
        int o    = mt * 16 + (lane & 15);
        int i    = (c & 1) * 32 + ((lane >> 4) << 3) + j;
        int kb   = c >> 1;
        wswz[idx] = (_Float16)W[(o * 64 + i) * 9 + kb];
    }
    if (idx < 128) stats[idx] = 0.0f;
}

// ---- kernel 2: fused GEMM + facet mean + bias + ReLU + BN-stat accumulation
__global__ __launch_bounds__(256, 2) void pass1_kernel(
    const float* __restrict__ X, const float* __restrict__ BARY,
    const _Float16* __restrict__ WSWZ, const float* __restrict__ BIAS,
    const int* __restrict__ NTEX, float* __restrict__ OUT,
    float* __restrict__ stats) {

    __shared__ float sl_s[64];
    __shared__ float sl_s2[64];

    const int tid  = threadIdx.x;
    const int wave = tid >> 6;
    const int lane = tid & 63;
    const int col  = lane & 15;   // texture within group / MFMA column
    const int quad = lane >> 4;

    // A-operand: this wave's 16 output channels, all K. 72 regs (AGPRs), resident whole kernel.
    half8 wf[18];
#pragma unroll
    for (int c = 0; c < 18; ++c)
        wf[c] = *(const half8*)(WSWZ + ((size_t)(c * 4 + wave) * 64 + lane) * 8);

    // bias for this lane's 4 channels: ch = wave*16 + quad*4 + r
    const f32x4 biasv = *(const f32x4*)(BIAS + wave * 16 + quad * 4);

    float sacc[4]  = {0.f, 0.f, 0.f, 0.f};
    float s2acc[4] = {0.f, 0.f, 0.f, 0.f};

    int g = blockIdx.x;

    // ---- prologue: load tile g into f32 staging registers
    f32x4  x0, x1, x2, x3;
    f32x4u b0, b1;
    float  b8;
    int    nt;
    {
        const int t = g * 16 + col;
        const float* xp = X + (size_t)t * 64 + quad * 8;
        x0 = *(const f32x4*)(xp);
        x1 = *(const f32x4*)(xp + 4);
        x2 = *(const f32x4*)(xp + 32);
        x3 = *(const f32x4*)(xp + 36);
        const float* bp = BARY + (size_t)t * 9;
        b0 = *(const f32x4u*)(bp);
        b1 = *(const f32x4u*)(bp + 4);
        b8 = bp[8];
        nt = NTEX[g * 4 + (col >> 2)];
    }

    while (g < NGROUPS) {
        // ---- convert current tile to f16 (frees the f32 staging registers)
        h2 xh[8], bh[9];
        xh[0] = pkrtz(x0[0], x0[1]);  xh[1] = pkrtz(x0[2], x0[3]);
        xh[2] = pkrtz(x1[0], x1[1]);  xh[3] = pkrtz(x1[2], x1[3]);
        xh[4] = pkrtz(x2[0], x2[1]);  xh[5] = pkrtz(x2[2], x2[3]);
        xh[6] = pkrtz(x3[0], x3[1]);  xh[7] = pkrtz(x3[2], x3[3]);
        bh[0] = pkrtz(b0[0], b0[0]);  bh[1] = pkrtz(b0[1], b0[1]);
        bh[2] = pkrtz(b0[2], b0[2]);  bh[3] = pkrtz(b0[3], b0[3]);
        bh[4] = pkrtz(b1[0], b1[0]);  bh[5] = pkrtz(b1[1], b1[1]);
        bh[6] = pkrtz(b1[2], b1[2]);  bh[7] = pkrtz(b1[3], b1[3]);
        bh[8] = pkrtz(b8, b8);
        const float rc = __builtin_amdgcn_rcpf((float)nt);  // exact for pow2 counts
        const int gcur = g;

        // ---- prefetch tile g+GRID1: loads in flight across the MFMA+reduce phase below
        g += GRID1;
        if (g < NGROUPS) {
            const int t = g * 16 + col;
            const float* xp = X + (size_t)t * 64 + quad * 8;
            x0 = *(const f32x4*)(xp);
            x1 = *(const f32x4*)(xp + 4);
            x2 = *(const f32x4*)(xp + 32);
            x3 = *(const f32x4*)(xp + 36);
            const float* bp = BARY + (size_t)t * 9;
            b0 = *(const f32x4u*)(bp);
            b1 = *(const f32x4u*)(bp + 4);
            b8 = bp[8];
            nt = NTEX[g * 4 + (col >> 2)];
        }

        // ---- 18 MFMAs as two independent 9-deep chains (even/odd chunks share bh[kb])
        f32x4 acc0 = {0.f, 0.f, 0.f, 0.f};
        f32x4 acc1 = {0.f, 0.f, 0.f, 0.f};
        __builtin_amdgcn_s_setprio(1);
#pragma unroll
        for (int c = 0; c < 18; c += 2) {
            const h2 bk = bh[c >> 1];
            HF bf0, bf1;
            bf0.h[0] = xh[0] * bk;
            bf0.h[1] = xh[1] * bk;
            bf0.h[2] = xh[2] * bk;
            bf0.h[3] = xh[3] * bk;
            acc0 = __builtin_amdgcn_mfma_f32_16x16x32_f16(wf[c], bf0.v, acc0, 0, 0, 0);
            bf1.h[0] = xh[4] * bk;
            bf1.h[1] = xh[5] * bk;
            bf1.h[2] = xh[6] * bk;
            bf1.h[3] = xh[7] * bk;
            acc1 = __builtin_amdgcn_mfma_f32_16x16x32_f16(wf[c + 1], bf1.v, acc1, 0, 0, 0);
        }
        __builtin_amdgcn_s_setprio(0);

        // ---- facet mean + bias + ReLU + stats + store (facet = 4 adjacent lanes)
        const int f = gcur * 4 + (col >> 2);
        f32x4 vv;
#pragma unroll
        for (int r = 0; r < 4; ++r) {
            float s = acc0[r] + acc1[r];
            s += __shfl_xor(s, 1);
            s += __shfl_xor(s, 2);
            s = s * rc + biasv[r];
            s = s > 0.f ? s : 0.f;
            vv[r] = s;
            sacc[r]  += s;         // every lane in the col-group holds same value:
            s2acc[r] += s * s;     // 4x overcount, corrected by 0.25 at the end
        }
        if ((col & 3) == 0)
            *(f32x4*)(OUT + (size_t)f * 64 + wave * 16 + quad * 4) = vv;
    }

    // reduce stats across the 16 cols (facet subsets); channels partitioned by (wave,quad,r)
#pragma unroll
    for (int r = 0; r < 4; ++r) {
        float s = sacc[r], s2 = s2acc[r];
        s  += __shfl_xor(s, 1);  s  += __shfl_xor(s, 2);
        s  += __shfl_xor(s, 4);  s  += __shfl_xor(s, 8);
        s2 += __shfl_xor(s2, 1); s2 += __shfl_xor(s2, 2);
        s2 += __shfl_xor(s2, 4); s2 += __shfl_xor(s2, 8);
        if (col == 0) {
            sl_s [wave * 16 + quad * 4 + r] = s  * 0.25f;
            sl_s2[wave * 16 + quad * 4 + r] = s2 * 0.25f;
        }
    }
    __syncthreads();
    if (tid < 64)        atomicAdd(&stats[tid],      sl_s [tid]);
    else if (tid < 128)  atomicAdd(&stats[tid],      sl_s2[tid - 64]);
}

// ---- kernel 3: in-place batch-norm normalize on OUT
__global__ __launch_bounds__(256) void pass3_kernel(float* __restrict__ OUT,
    const float* __restrict__ stats, const float* __restrict__ gamma,
    const float* __restrict__ beta) {
    const int tid = threadIdx.x;
    const size_t l = (size_t)blockIdx.x * 256 + tid;
    const int c0 = ((int)l & 15) * 4;     // grid*256 is a multiple of 16 -> constant per thread
    float mu[4], sc[4], be[4];
    const float invF = 1.0f / (float)FFACETS;
#pragma unroll
    for (int u = 0; u < 4; ++u) {
        int ch = c0 + u;
        float m  = stats[ch] * invF;
        float va = stats[64 + ch] * invF - m * m;
        mu[u] = m;
        sc[u] = rsqrtf(va + 1e-3f) * gamma[ch];
        be[u] = beta[ch];
    }
    const size_t n4 = (size_t)FFACETS * 16;
    for (size_t i = l; i < n4; i += (size_t)gridDim.x * 256) {
        f32x4 v = ((f32x4*)OUT)[i];
#pragma unroll
        for (int u = 0; u < 4; ++u)
            v[u] = (v[u] - mu[u]) * sc[u] + be[u];
        ((f32x4*)OUT)[i] = v;
    }
}

extern "C" void kernel_launch(void* const* d_in, const int* in_sizes, int n_in,
                              void* d_out, int out_size, void* d_ws, size_t ws_size,
                              hipStream_t stream) {
    const float* X     = (const float*)d_in[0];
    const float* BARY  = (const float*)d_in[1];
    const float* W     = (const float*)d_in[2];
    const float* BIAS  = (const float*)d_in[3];
    const float* GAMMA = (const float*)d_in[4];
    const float* BETA  = (const float*)d_in[5];
    const int*   NTEX  = (const int*)d_in[6];
    float* OUT = (float*)d_out;

    _Float16* wswz = (_Float16*)d_ws;                       // 73728 B
    float* stats   = (float*)((char*)d_ws + 73728);         // 128 floats

    prep_kernel<<<144, 256, 0, stream>>>(W, wswz, stats);
    pass1_kernel<<<GRID1, 256, 0, stream>>>(X, BARY, wswz, BIAS, NTEX, OUT, stats);
    pass3_kernel<<<2048, 256, 0, stream>>>(OUT, stats, GAMMA, BETA);
}

// Round 2
// 687.880 us; speedup vs baseline: 1.2704x; 1.0800x over previous
//
#include <hip/hip_runtime.h>

// F2FConv3d on MI355X.
// contrib = (x ⊗ bary) @ Wflat  as f16 MFMA (16x16x32), W = A-operand in registers (AGPRs).
// K ordering: p = kbasis*64 + i  (chunk c of 32: kbasis = c>>1, i = (c&1)*32 + [0,32)).
// Wave w owns output channels [w*16, w*16+16): A-frags = 18 x half8 = 72 regs, loaded once.
//
// V3: block-shared LDS staging of the group tile (X 4KB + BARY 576B + NTEX 16B) via
//     global_load_lds (async, direct-to-LDS), double-buffered, DEPTH-2 counted vmcnt
//     (steady vmcnt(4), never 0 in the loop), raw s_barrier (NOT __syncthreads — that
//     drains vmcnt). Dedups the 4x redundant per-wave global loads of X/BARY.
//     X LDS layout XOR-swizzled (bits 4-6 ^= col&7) to kill the 16-way ds_read_b128
//     bank conflict; swizzle applied on the GLOBAL SOURCE address (linear LDS dest,
//     Guideline 21) and on the read address.  launch_bounds(256,3) -> 3 blocks/CU.
//
// D layout (measured, m89): row = quad*4 + reg (channel), col = lane&15 (texture)
//   -> facet (4 consecutive textures) = shfl_xor 1,2 across lanes.

typedef _Float16 half8  __attribute__((ext_vector_type(8)));
typedef _Float16 h2     __attribute__((ext_vector_type(2)));
typedef __fp16   fp16x2 __attribute__((ext_vector_type(2)));
typedef float    f32x4  __attribute__((ext_vector_type(4)));

#define NGROUPS 100000   // 1.6M textures / 16 per group
#define FFACETS 400000
#define GRID1   768      // 3 blocks/CU x 256 CUs, exactly resident
#define LDSBUF  8192     // per parity: X[0,4096) | BARY[4096,4672) | NTEX[4672,4688)

#define WAITV(N) asm volatile("s_waitcnt vmcnt(" #N ")" ::: "memory")
#define FENCE()  asm volatile("" ::: "memory")

union HF { h2 h[4]; half8 v; };

static __device__ __forceinline__ h2 pkrtz(float a, float b) {
    fp16x2 r = __builtin_amdgcn_cvt_pkrtz(a, b);
    return __builtin_bit_cast(h2, r);
}

static __device__ __forceinline__ void gload16(const void* g, void* l) {
    __builtin_amdgcn_global_load_lds((const __attribute__((address_space(1))) void*)g,
                                     (__attribute__((address_space(3))) void*)l, 16, 0, 0);
}

// ---- kernel 1: swizzle W (fp32 [64][64][9]) -> f16 fragment order in ws, zero stats
__global__ __launch_bounds__(256) void prep_kernel(const float* __restrict__ W,
                                                   _Float16* __restrict__ wswz,
                                                   float* __restrict__ stats) {
    int idx = blockIdx.x * 256 + threadIdx.x;
    if (idx < 36864) {
        int j    = idx & 7;
        int lane = (idx >> 3) & 63;
        int mt   = (idx >> 9) & 3;        // which wave (channel tile)
        int c    = idx >> 11;             // K chunk 0..17
        int o    = mt * 16 + (lane & 15);
        int i    = (c & 1) * 32 + ((lane >> 4) << 3) + j;
        int kb   = c >> 1;
        wswz[idx] = (_Float16)W[(o * 64 + i) * 9 + kb];
    }
    if (idx < 128) stats[idx] = 0.0f;
}

// ---- kernel 2: fused GEMM + facet mean + bias + ReLU + BN-stat accumulation
__global__ __launch_bounds__(256, 3) void pass1_kernel(
    const float* __restrict__ X, const float* __restrict__ BARY,
    const _Float16* __restrict__ WSWZ, const float* __restrict__ BIAS,
    const int* __restrict__ NTEX, float* __restrict__ OUT,
    float* __restrict__ stats) {

    __shared__ __align__(16) char lds[2][LDSBUF];
    __shared__ float sl_s[64];
    __shared__ float sl_s2[64];

    const int tid  = threadIdx.x;
    const int wave = tid >> 6;
    const int lane = tid & 63;
    const int col  = lane & 15;   // texture within group / MFMA column
    const int quad = lane >> 4;

    // A-operand: this wave's 16 output channels, all K. 72 regs (AGPRs), resident whole kernel.
    half8 wf[18];
#pragma unroll
    for (int c = 0; c < 18; ++c)
        wf[c] = *(const half8*)(WSWZ + ((size_t)(c * 4 + wave) * 64 + lane) * 8);

    // bias for this lane's 4 channels: ch = wave*16 + quad*4 + r
    const f32x4 biasv = *(const f32x4*)(BIAS + wave * 16 + quad * 4);

    // ---- stage-side per-thread constants (linear LDS dest, pre-swizzled global src)
    const int pphys  = (wave << 10) + (lane << 4);           // this thread's X dst byte in buf
    const int xsoff  = pphys ^ (((pphys >> 8) & 7) << 4);    // inverse-swizzled global byte off
    const char* Xb   = (const char*)X;
    const char* BNb  = (lane < 36) ? ((const char*)BARY + lane * 16) : (const char*)NTEX;

    // ---- read-side per-thread constants (swizzled X addresses; 2-way max bank alias)
    const int m    = (col & 7) << 4;
    const int a00  = (col << 8) + ((quad << 5) ^ m);
    const int a10  = (col << 8) + (((quad << 5) | 16) ^ m);
    const int bco  = 4096 + col * 36;                        // stride 36B: conflict-free
    const int nco  = 4096 + 576 + ((col >> 2) << 2);

    float sacc[4]  = {0.f, 0.f, 0.f, 0.f};
    float s2acc[4] = {0.f, 0.f, 0.f, 0.f};

    const int b = blockIdx.x;
    const int n = (NGROUPS - 1 - b) / GRID1 + 1;             // uniform across the block

    auto STAGE = [&](int p, int g) {
        gload16(Xb + (size_t)g * 4096 + xsoff, &lds[p][pphys]);
        if (lane < 37) {   // lanes 0-35: BARY row-block; lane 36: NTEX quad (redundant across waves)
            size_t so = (lane < 36) ? (size_t)g * 576 : (size_t)g * 16;
            gload16(BNb + so, &lds[p][4096 + lane * 16]);
        }
    };

    auto ITER = [&](int p, int g, int gpre, bool do_stage) {
        __builtin_amdgcn_s_barrier();          // caller did WAITV: stage_t landed for all waves
        FENCE();
        // ---- LDS reads (4x ds_read_b128 swizzled + 9x b32 + 1x b32)
        f32x4 r00 = *(const f32x4*)&lds[p][a00];
        f32x4 r10 = *(const f32x4*)&lds[p][a10];
        f32x4 r01 = *(const f32x4*)&lds[p][a00 + 128];
        f32x4 r11 = *(const f32x4*)&lds[p][a10 + 128];
        float bF[9];
#pragma unroll
        for (int k = 0; k < 9; ++k) bF[k] = *(const float*)&lds[p][bco + k * 4];
        const int nt = *(const int*)&lds[p][nco];
        asm volatile("s_waitcnt lgkmcnt(0)" ::: "memory");   // reads done before overwrite
        __builtin_amdgcn_sched_barrier(0);
        __builtin_amdgcn_s_barrier();          // all waves finished reading buf p
        FENCE();
        if (do_stage) STAGE(p, gpre);          // t+2 loads fly across the next 2 iterations
        FENCE();                                // pin stage before store in vmcnt queue order

        // ---- convert current tile to f16
        h2 xh[8], bh[9];
        xh[0] = pkrtz(r00[0], r00[1]);  xh[1] = pkrtz(r00[2], r00[3]);
        xh[2] = pkrtz(r10[0], r10[1]);  xh[3] = pkrtz(r10[2], r10[3]);
        xh[4] = pkrtz(r01[0], r01[1]);  xh[5] = pkrtz(r01[2], r01[3]);
        xh[6] = pkrtz(r11[0], r11[1]);  xh[7] = pkrtz(r11[2], r11[3]);
#pragma unroll
        for (int k = 0; k < 9; ++k) bh[k] = pkrtz(bF[k], bF[k]);
        const float rc = __builtin_amdgcn_rcpf((float)nt);   // exact for pow2 counts

        // ---- 18 MFMAs as two independent 9-deep chains
        f32x4 acc0 = {0.f, 0.f, 0.f, 0.f};
        f32x4 acc1 = {0.f, 0.f, 0.f, 0.f};
        __builtin_amdgcn_s_setprio(1);
#pragma unroll
        for (int c = 0; c < 18; c += 2) {
            const h2 bk = bh[c >> 1];
            HF bf0, bf1;
            bf0.h[0] = xh[0] * bk;  bf0.h[1] = xh[1] * bk;
            bf0.h[2] = xh[2] * bk;  bf0.h[3] = xh[3] * bk;
            acc0 = __builtin_amdgcn_mfma_f32_16x16x32_f16(wf[c], bf0.v, acc0, 0, 0, 0);
            bf1.h[0] = xh[4] * bk;  bf1.h[1] = xh[5] * bk;
            bf1.h[2] = xh[6] * bk;  bf1.h[3] = xh[7] * bk;
            acc1 = __builtin_amdgcn_mfma_f32_16x16x32_f16(wf[c + 1], bf1.v, acc1, 0, 0, 0);
        }
        __builtin_amdgcn_s_setprio(0);

        // ---- facet mean + bias + ReLU + stats + store (facet = 4 adjacent lanes)
        const int f = g * 4 + (col >> 2);
        f32x4 vv;
#pragma unroll
        for (int r = 0; r < 4; ++r) {
            float s = acc0[r] + acc1[r];
            s += __shfl_xor(s, 1);
            s += __shfl_xor(s, 2);
            s = s * rc + biasv[r];
            s = s > 0.f ? s : 0.f;
            vv[r] = s;
            sacc[r]  += s;         // every lane in the col-group holds same value:
            s2acc[r] += s * s;     // 4x overcount, corrected by 0.25 at the end
        }
        if ((col & 3) == 0)
            *(f32x4*)(OUT + (size_t)f * 64 + wave * 16 + quad * 4) = vv;
    };

    // ---- software pipeline: depth-2, counted vmcnt (per-iter queue = [stageX,stageBN,store])
    STAGE(0, b);
    STAGE(1, b + GRID1);
    WAITV(2); ITER(0, b,         b + 2 * GRID1, true);   // also drains wf prologue loads
    WAITV(3); ITER(1, b + GRID1, b + 3 * GRID1, true);
    int t = 2;
    for (; t < n - 2; ++t) {
        WAITV(4);
        ITER(t & 1, b + t * GRID1, b + (t + 2) * GRID1, true);
    }
    WAITV(4); ITER(t & 1, b + t * GRID1, 0, false); ++t;
    WAITV(0); ITER(t & 1, b + t * GRID1, 0, false);

    // reduce stats across the 16 cols (facet subsets); channels partitioned by (wave,quad,r)
#pragma unroll
    for (int r = 0; r < 4; ++r) {
        float s = sacc[r], s2 = s2acc[r];
        s  += __shfl_xor(s, 1);  s  += __shfl_xor(s, 2);
        s  += __shfl_xor(s, 4);  s  += __shfl_xor(s, 8);
        s2 += __shfl_xor(s2, 1); s2 += __shfl_xor(s2, 2);
        s2 += __shfl_xor(s2, 4); s2 += __shfl_xor(s2, 8);
        if (col == 0) {
            sl_s [wave * 16 + quad * 4 + r] = s  * 0.25f;
            sl_s2[wave * 16 + quad * 4 + r] = s2 * 0.25f;
        }
    }
    __syncthreads();
    if (tid < 64)        atomicAdd(&stats[tid],      sl_s [tid]);
    else if (tid < 128)  atomicAdd(&stats[tid],      sl_s2[tid - 64]);
}

// ---- kernel 3: in-place batch-norm normalize on OUT
__global__ __launch_bounds__(256) void pass3_kernel(float* __restrict__ OUT,
    const float* __restrict__ stats, const float* __restrict__ gamma,
    const float* __restrict__ beta) {
    const int tid = threadIdx.x;
    const size_t l = (size_t)blockIdx.x * 256 + tid;
    const int c0 = ((int)l & 15) * 4;     // grid*256 is a multiple of 16 -> constant per thread
    float mu[4], sc[4], be[4];
    const float invF = 1.0f / (float)FFACETS;
#pragma unroll
    for (int u = 0; u < 4; ++u) {
        int ch = c0 + u;
        float m  = stats[ch] * invF;
        float va = stats[64 + ch] * invF - m * m;
        mu[u] = m;
        sc[u] = rsqrtf(va + 1e-3f) * gamma[ch];
        be[u] = beta[ch];
    }
    const size_t n4 = (size_t)FFACETS * 16;
    for (size_t i = l; i < n4; i += (size_t)gridDim.x * 256) {
        f32x4 v = ((f32x4*)OUT)[i];
#pragma unroll
        for (int u = 0; u < 4; ++u)
            v[u] = (v[u] - mu[u]) * sc[u] + be[u];
        ((f32x4*)OUT)[i] = v;
    }
}

extern "C" void kernel_launch(void* const* d_in, const int* in_sizes, int n_in,
                              void* d_out, int out_size, void* d_ws, size_t ws_size,
                              hipStream_t stream) {
    const float* X     = (const float*)d_in[0];
    const float* BARY  = (const float*)d_in[1];
    const float* W     = (const float*)d_in[2];
    const float* BIAS  = (const float*)d_in[3];
    const float* GAMMA = (const float*)d_in[4];
    const float* BETA  = (const float*)d_in[5];
    const int*   NTEX  = (const int*)d_in[6];
    float* OUT = (float*)d_out;

    _Float16* wswz = (_Float16*)d_ws;                       // 73728 B
    float* stats   = (float*)((char*)d_ws + 73728);         // 128 floats

    prep_kernel<<<144, 256, 0, stream>>>(W, wswz, stats);
    pass1_kernel<<<GRID1, 256, 0, stream>>>(X, BARY, wswz, BIAS, NTEX, OUT, stats);
    pass3_kernel<<<2048, 256, 0, stream>>>(OUT, stats, GAMMA, BETA);
}

// Round 3
// 674.353 us; speedup vs baseline: 1.2959x; 1.0201x over previous
//
#include <hip/hip_runtime.h>

// F2FConv3d on MI355X.
// contrib = (x ⊗ bary) @ Wflat  as f16 MFMA (16x16x32), W = A-operand in registers (AGPRs).
// K ordering: p = kbasis*64 + i  (chunk c of 32: kbasis = c>>1, i = (c&1)*32 + [0,32)).
// Wave w owns output channels [w*16, w*16+16): A-frags = 18 x half8 = 72 regs, loaded once.
//
// V4: 2 GROUPS PER BUFFER PARITY. A group-pair's X (8KB), BARY (1152B), NTEX (32B) are
//     contiguous in global memory -> staged with 5 global_load_lds per wave (linear LDS
//     dest, pre-swizzled global src per 4KB half). Halves barriers/vmcnt-waits per group,
//     doubles the latency window (depth-2 pairs = 4 groups in flight). The two groups'
//     18-MFMA chains interleave (2 independent chains); g0 epilogue overlaps g1 MFMAs.
//     Steady-state vmcnt(9), never 0 in the loop. Raw s_barrier (NOT __syncthreads).
//     X LDS layout XOR-swizzled (bits 4-6 ^= col&7): conflict-free ds_read_b128.
//     launch_bounds(256,3) -> 3 blocks/CU (peak ~85 VGPR + 80 AGPR = 165 <= 170).
//
// D layout (measured, m89): row = quad*4 + reg (channel), col = lane&15 (texture)
//   -> facet (4 consecutive textures) = shfl_xor 1,2 across lanes.

typedef _Float16 half8  __attribute__((ext_vector_type(8)));
typedef _Float16 h2     __attribute__((ext_vector_type(2)));
typedef __fp16   fp16x2 __attribute__((ext_vector_type(2)));
typedef float    f32x4  __attribute__((ext_vector_type(4)));

#define NGROUPS 100000   // 1.6M textures / 16 per group
#define NPAIRS  50000    // groups staged in pairs (8KB X contiguous)
#define FFACETS 400000
#define GRID1   768      // 3 blocks/CU x 256 CUs, exactly resident
#define LDSP    9472     // per parity: X[0,8192) | BARY[8192,9344) | NTEX[9344,9376)

#define WAITV(N) asm volatile("s_waitcnt vmcnt(" #N ")" ::: "memory")
#define WAITL0() asm volatile("s_waitcnt lgkmcnt(0)" ::: "memory")
#define FENCE()  asm volatile("" ::: "memory")
#define SB0()    __builtin_amdgcn_sched_barrier(0)

union HF { h2 h[4]; half8 v; };

static __device__ __forceinline__ h2 pkrtz(float a, float b) {
    fp16x2 r = __builtin_amdgcn_cvt_pkrtz(a, b);
    return __builtin_bit_cast(h2, r);
}

static __device__ __forceinline__ void gload16(const void* g, void* l) {
    __builtin_amdgcn_global_load_lds((const __attribute__((address_space(1))) void*)g,
                                     (__attribute__((address_space(3))) void*)l, 16, 0, 0);
}

// ---- kernel 1: swizzle W (fp32 [64][64][9]) -> f16 fragment order in ws, zero stats
__global__ __launch_bounds__(256) void prep_kernel(const float* __restrict__ W,
                                                   _Float16* __restrict__ wswz,
                                                   float* __restrict__ stats) {
    int idx = blockIdx.x * 256 + threadIdx.x;
    if (idx < 36864) {
        int j    = idx & 7;
        int lane = (idx >> 3) & 63;
        int mt   = (idx >> 9) & 3;        // which wave (channel tile)
        int c    = idx >> 11;             // K chunk 0..17
        int o    = mt * 16 + (lane & 15);
        int i    = (c & 1) * 32 + ((lane >> 4) << 3) + j;
        int kb   = c >> 1;
        wswz[idx] = (_Float16)W[(o * 64 + i) * 9 + kb];
    }
    if (idx < 128) stats[idx] = 0.0f;
}

// ---- kernel 2: fused GEMM + facet mean + bias + ReLU + BN-stat accumulation
__global__ __launch_bounds__(256, 3) void pass1_kernel(
    const float* __restrict__ X, const float* __restrict__ BARY,
    const _Float16* __restrict__ WSWZ, const float* __restrict__ BIAS,
    const int* __restrict__ NTEX, float* __restrict__ OUT,
    float* __restrict__ stats) {

    __shared__ __align__(16) char lds[2][LDSP];
    __shared__ float sl_s[64];
    __shared__ float sl_s2[64];

    const int tid  = threadIdx.x;
    const int wave = tid >> 6;
    const int lane = tid & 63;
    const int col  = lane & 15;   // texture within group / MFMA column
    const int quad = lane >> 4;

    // A-operand: this wave's 16 output channels, all K. 72 regs (AGPRs), resident whole kernel.
    half8 wf[18];
#pragma unroll
    for (int c = 0; c < 18; ++c)
        wf[c] = *(const half8*)(WSWZ + ((size_t)(c * 4 + wave) * 64 + lane) * 8);

    // bias for this lane's 4 channels: ch = wave*16 + quad*4 + r
    const f32x4 biasv = *(const f32x4*)(BIAS + wave * 16 + quad * 4);

    // ---- stage-side per-thread constants (linear LDS dest, pre-swizzled global src)
    const int pphys  = (wave << 10) + (lane << 4);           // X dst byte within a 4KB half
    const int xsoff  = pphys ^ (((pphys >> 8) & 7) << 4);    // inverse-swizzled global byte off
    const char* Xb   = (const char*)X;
    const char* BAb  = (const char*)BARY;
    const char* NTb  = (const char*)NTEX;

    // ---- read-side per-thread constants (swizzled X addresses; conflict-free b128)
    const int m    = (col & 7) << 4;
    const int a00  = (col << 8) + ((quad << 5) ^ m);
    const int a10  = (col << 8) + (((quad << 5) | 16) ^ m);
    const int bco  = 8192 + col * 36;                        // stride 36B: conflict-free
    const int nco  = 9344 + ((col >> 2) << 2);

    float sacc[4]  = {0.f, 0.f, 0.f, 0.f};
    float s2acc[4] = {0.f, 0.f, 0.f, 0.f};

    const int b = blockIdx.x;
    const int n = (NPAIRS - 1 - b) / GRID1 + 1;              // pairs for this block (uniform)

    // 5 vmem ops per wave per STAGE (uniform across waves; BARY/NTEX staged redundantly
    // by all 4 waves to identical LDS bytes -> benign, keeps vmcnt bookkeeping uniform)
    auto STAGE = [&](int p, int u) {
        const char* xs = Xb + (size_t)u * 8192;
        gload16(xs + xsoff,        &lds[p][pphys]);
        gload16(xs + 4096 + xsoff, &lds[p][4096 + pphys]);
        gload16(BAb + (size_t)u * 1152 + lane * 16, &lds[p][8192 + lane * 16]);
        if (lane < 8) gload16(BAb + (size_t)u * 1152 + 1024 + lane * 16, &lds[p][9216 + lane * 16]);
        if (lane < 2) gload16(NTb + (size_t)u * 32 + lane * 16,          &lds[p][9344 + lane * 16]);
    };

    auto EPI = [&](f32x4 acc, float rc, int f) {
        f32x4 vv;
#pragma unroll
        for (int r = 0; r < 4; ++r) {
            float s = acc[r];
            s += __shfl_xor(s, 1);
            s += __shfl_xor(s, 2);
            s = s * rc + biasv[r];
            s = s > 0.f ? s : 0.f;
            vv[r] = s;
            sacc[r]  += s;         // every lane in the col-group holds same value:
            s2acc[r] += s * s;     // 4x overcount, corrected by 0.25 at the end
        }
        if ((col & 3) == 0)
            *(f32x4*)(OUT + (size_t)f * 64 + wave * 16 + quad * 4) = vv;
    };

    auto ITER = [&](int p, int u, int upre, bool do_stage) {
        __builtin_amdgcn_s_barrier();          // caller did WAITV: stage(u) landed for all waves
        FENCE();
        const char* L = lds[p];
        // ---- LDS reads for both groups (8x b128 swizzled + 18x b32 + 2x b32, all in flight)
        f32x4 r0[4], r1[4];
        r0[0] = *(const f32x4*)(L + a00);
        r0[1] = *(const f32x4*)(L + a10);
        r0[2] = *(const f32x4*)(L + a00 + 128);
        r0[3] = *(const f32x4*)(L + a10 + 128);
        r1[0] = *(const f32x4*)(L + 4096 + a00);
        r1[1] = *(const f32x4*)(L + 4096 + a10);
        r1[2] = *(const f32x4*)(L + 4096 + a00 + 128);
        r1[3] = *(const f32x4*)(L + 4096 + a10 + 128);
        float bF0[9], bF1[9];
#pragma unroll
        for (int k = 0; k < 9; ++k) bF0[k] = *(const float*)(L + bco + k * 4);
#pragma unroll
        for (int k = 0; k < 9; ++k) bF1[k] = *(const float*)(L + bco + 576 + k * 4);
        const int nt0 = *(const int*)(L + nco);
        const int nt1 = *(const int*)(L + nco + 16);

        // ---- convert to f16 (frees the f32 staging registers)
        h2 xh0[8], xh1[8], bh0[9], bh1[9];
        xh0[0] = pkrtz(r0[0][0], r0[0][1]);  xh0[1] = pkrtz(r0[0][2], r0[0][3]);
        xh0[2] = pkrtz(r0[1][0], r0[1][1]);  xh0[3] = pkrtz(r0[1][2], r0[1][3]);
        xh0[4] = pkrtz(r0[2][0], r0[2][1]);  xh0[5] = pkrtz(r0[2][2], r0[2][3]);
        xh0[6] = pkrtz(r0[3][0], r0[3][1]);  xh0[7] = pkrtz(r0[3][2], r0[3][3]);
        xh1[0] = pkrtz(r1[0][0], r1[0][1]);  xh1[1] = pkrtz(r1[0][2], r1[0][3]);
        xh1[2] = pkrtz(r1[1][0], r1[1][1]);  xh1[3] = pkrtz(r1[1][2], r1[1][3]);
        xh1[4] = pkrtz(r1[2][0], r1[2][1]);  xh1[5] = pkrtz(r1[2][2], r1[2][3]);
        xh1[6] = pkrtz(r1[3][0], r1[3][1]);  xh1[7] = pkrtz(r1[3][2], r1[3][3]);
#pragma unroll
        for (int k = 0; k < 9; ++k) { bh0[k] = pkrtz(bF0[k], bF0[k]); bh1[k] = pkrtz(bF1[k], bF1[k]); }
        const float rc0 = __builtin_amdgcn_rcpf((float)nt0);   // exact for pow2 counts
        const float rc1 = __builtin_amdgcn_rcpf((float)nt1);

        WAITL0();                              // all reads of buf p done before overwrite
        SB0();
        __builtin_amdgcn_s_barrier();          // all waves finished reading buf p
        FENCE();
        if (do_stage) STAGE(p, upre);          // pair u+2: flies across the next 2 iterations
        FENCE();                               // pin stage before stores in vmcnt queue order

        // ---- 36 MFMAs as two independent 18-chains (g0/g1 interleaved)
        f32x4 accA = {0.f, 0.f, 0.f, 0.f};
        f32x4 accB = {0.f, 0.f, 0.f, 0.f};
        __builtin_amdgcn_s_setprio(1);
#pragma unroll
        for (int c = 0; c < 18; ++c) {
            const int hh = (c & 1) * 4;
            const h2 bkA = bh0[c >> 1];
            const h2 bkB = bh1[c >> 1];
            HF fa, fb;
            fa.h[0] = xh0[hh + 0] * bkA;  fa.h[1] = xh0[hh + 1] * bkA;
            fa.h[2] = xh0[hh + 2] * bkA;  fa.h[3] = xh0[hh + 3] * bkA;
            accA = __builtin_amdgcn_mfma_f32_16x16x32_f16(wf[c], fa.v, accA, 0, 0, 0);
            fb.h[0] = xh1[hh + 0] * bkB;  fb.h[1] = xh1[hh + 1] * bkB;
            fb.h[2] = xh1[hh + 2] * bkB;  fb.h[3] = xh1[hh + 3] * bkB;
            accB = __builtin_amdgcn_mfma_f32_16x16x32_f16(wf[c], fb.v, accB, 0, 0, 0);
        }
        __builtin_amdgcn_s_setprio(0);

        // ---- facet mean + bias + ReLU + stats + store (facet = 4 adjacent lanes)
        const int f0 = u * 8 + (col >> 2);
        EPI(accA, rc0, f0);
        EPI(accB, rc1, f0 + 4);
    };

    // ---- software pipeline: depth-2 pairs, counted vmcnt
    // per-iter vmem queue per wave: [stage:5][stores:2] -> steady wait = 2+5+2 = 9
    STAGE(0, b);
    STAGE(1, b + GRID1);
    WAITV(5); ITER(0, b,         b + 2 * GRID1, true);   // also drains wf prologue loads
    WAITV(7); ITER(1, b + GRID1, b + 3 * GRID1, true);
    int t = 2;
    for (; t < n - 2; ++t) {
        WAITV(9);
        ITER(t & 1, b + t * GRID1, b + (t + 2) * GRID1, true);
    }
    WAITV(9); ITER(t & 1, b + t * GRID1, 0, false); ++t;   // t = n-2
    WAITV(4); ITER(t & 1, b + t * GRID1, 0, false);        // t = n-1

    // reduce stats across the 16 cols (facet subsets); channels partitioned by (wave,quad,r)
#pragma unroll
    for (int r = 0; r < 4; ++r) {
        float s = sacc[r], s2 = s2acc[r];
        s  += __shfl_xor(s, 1);  s  += __shfl_xor(s, 2);
        s  += __shfl_xor(s, 4);  s  += __shfl_xor(s, 8);
        s2 += __shfl_xor(s2, 1); s2 += __shfl_xor(s2, 2);
        s2 += __shfl_xor(s2, 4); s2 += __shfl_xor(s2, 8);
        if (col == 0) {
            sl_s [wave * 16 + quad * 4 + r] = s  * 0.25f;
            sl_s2[wave * 16 + quad * 4 + r] = s2 * 0.25f;
        }
    }
    __syncthreads();
    if (tid < 64)        atomicAdd(&stats[tid],      sl_s [tid]);
    else if (tid < 128)  atomicAdd(&stats[tid],      sl_s2[tid - 64]);
}

// ---- kernel 3: in-place batch-norm normalize on OUT
__global__ __launch_bounds__(256) void pass3_kernel(float* __restrict__ OUT,
    const float* __restrict__ stats, const float* __restrict__ gamma,
    const float* __restrict__ beta) {
    const int tid = threadIdx.x;
    const size_t l = (size_t)blockIdx.x * 256 + tid;
    const int c0 = ((int)l & 15) * 4;     // grid*256 is a multiple of 16 -> constant per thread
    float mu[4], sc[4], be[4];
    const float invF = 1.0f / (float)FFACETS;
#pragma unroll
    for (int u = 0; u < 4; ++u) {
        int ch = c0 + u;
        float m  = stats[ch] * invF;
        float va = stats[64 + ch] * invF - m * m;
        mu[u] = m;
        sc[u] = rsqrtf(va + 1e-3f) * gamma[ch];
        be[u] = beta[ch];
    }
    const size_t n4 = (size_t)FFACETS * 16;
    for (size_t i = l; i < n4; i += (size_t)gridDim.x * 256) {
        f32x4 v = ((f32x4*)OUT)[i];
#pragma unroll
        for (int u = 0; u < 4; ++u)
            v[u] = (v[u] - mu[u]) * sc[u] + be[u];
        ((f32x4*)OUT)[i] = v;
    }
}

extern "C" void kernel_launch(void* const* d_in, const int* in_sizes, int n_in,
                              void* d_out, int out_size, void* d_ws, size_t ws_size,
                              hipStream_t stream) {
    const float* X     = (const float*)d_in[0];
    const float* BARY  = (const float*)d_in[1];
    const float* W     = (const float*)d_in[2];
    const float* BIAS  = (const float*)d_in[3];
    const float* GAMMA = (const float*)d_in[4];
    const float* BETA  = (const float*)d_in[5];
    const int*   NTEX  = (const int*)d_in[6];
    float* OUT = (float*)d_out;

    _Float16* wswz = (_Float16*)d_ws;                       // 73728 B
    float* stats   = (float*)((char*)d_ws + 73728);         // 128 floats

    prep_kernel<<<144, 256, 0, stream>>>(W, wswz, stats);
    pass1_kernel<<<GRID1, 256, 0, stream>>>(X, BARY, wswz, BIAS, NTEX, OUT, stats);
    pass3_kernel<<<2048, 256, 0, stream>>>(OUT, stats, GAMMA, BETA);
}